// Round 7
// baseline (153.515 us; speedup 1.0000x reference)
//
#include <hip/hip_runtime.h>
#include <math.h>
#include <stdint.h>

#define NB 128      // batch
#define LQ 32       // query tokens
#define LD 180      // doc tokens
#define DD 128      // feature dim
#define NW 8        // nway
#define NBW (NB*NW)
#define PB 40       // bf16 row pitch (80 B: 16B-aligned rows)
#define LROWS 192   // doc rows padded to 6 tiles of 32 (pad rows zeroed once)

typedef __attribute__((ext_vector_type(8)))  short short8v;
typedef __attribute__((ext_vector_type(16))) float f32x16;

// Barrier WITHOUT vmcnt drain (keeps global->VGPR prefetch in flight).
static __device__ __forceinline__ void bar() {
    asm volatile("s_waitcnt lgkmcnt(0)" ::: "memory");
    __builtin_amdgcn_s_barrier();
}

// truncation f32 -> (hi,lo) bf16 split: rel err ~2^-16, far under budget
static __device__ __forceinline__ void split2(float x, short& h, short& l) {
    uint32_t u = __float_as_uint(x);
    h = (short)(u >> 16);
    float r = x - __uint_as_float(u & 0xffff0000u);
    l = (short)(__float_as_uint(r) >> 16);
}

// ---------- MaxSim: single doc pass, double-buffered, wave role-split ----------
// grid NBW x 512 (8 waves, 2 blocks/CU by LDS). Per chunk cc:
//   [all]     stage chunk cc+1 -> buf B (masked, split, ssq partials)
//   bar
//   [w0-5]    MFMA chunk cc from buf A            (in parallel)
//   [w6-7]    dinv(cc+1) + fold q'(cc+1) -> buf B (in parallel)
//   bar
__global__ __launch_bounds__(512, 4) void maxsim_kernel(
    const float* __restrict__ qreps, const float* __restrict__ dreps,
    const int* __restrict__ dmask, float* __restrict__ scores)
{
    __shared__ short s_dh[2][LROWS * PB];   // 30720 B
    __shared__ short s_dl[2][LROWS * PB];   // 30720 B
    __shared__ short s_qh[2][LQ * PB];      //  5120 B
    __shared__ short s_ql[2][LQ * PB];      //  5120 B
    __shared__ float s_ssq[2][8][32];       //  2048 B
    __shared__ float s_dinv[2][2][32];      //   512 B (per-wave-pair private copies)
    __shared__ float s_qinv[LQ];
    __shared__ float s_pm[6][LQ];           // total ~73.4 KB -> 2 blocks/CU

    const int t = threadIdx.x, bw = blockIdx.x, b = bw >> 3;
    const int lane = t & 63, wave = t >> 6;
    const int d4 = t & 7;        // feature quad within chunk
    const int rb = t >> 3;       // 0..63: doc row phase
    const int lh = lane >> 5, l31 = lane & 31;
    const bool has2 = (rb < 52);

    const float4* doc4 = (const float4*)(dreps + (size_t)bw * LD * DD);
    const float4* q4g  = (const float4*)(qreps + (size_t)b * LQ * DD);
    const int*    mrow = dmask + bw * LD;

    // ---- prefetch chunk 0 ----
    float4 dv0 = doc4[rb * 32 + d4];
    float4 dv1 = doc4[(rb + 64) * 32 + d4];
    float4 dv2 = make_float4(0.f, 0.f, 0.f, 0.f);
    if (has2) dv2 = doc4[(rb + 128) * 32 + d4];
    float4 qv0;
    if (t < 256) qv0 = q4g[rb * 32 + d4];
    float4 qf0, qf1;   // loop q prefetch (waves 6-7)

    const float mk0 = (float)mrow[rb];
    const float mk1 = (float)mrow[rb + 64];
    const float mk2 = has2 ? (float)mrow[rb + 128] : 0.0f;

    // ---- query row inv-norms (overlaps doc prefetch latency) ----
    {
        int r = t >> 4, sub = t & 15;
        float4 a = q4g[r * 32 + sub];
        float4 c = q4g[r * 32 + 16 + sub];
        float ss = a.x*a.x + a.y*a.y + a.z*a.z + a.w*a.w
                 + c.x*c.x + c.y*c.y + c.z*c.z + c.w*c.w;
        ss += __shfl_xor(ss, 8);
        ss += __shfl_xor(ss, 4);
        ss += __shfl_xor(ss, 2);
        ss += __shfl_xor(ss, 1);
        if (sub == 0) s_qinv[r] = 1.0f / fmaxf(sqrtf(ss), 1e-12f);
    }
    // ---- zero pad rows 180..191 once, both buffers ----
    if (rb >= 52) {
        short4 z = make_short4(0, 0, 0, 0);
        int off = (rb + 128) * PB + 4 * d4;
        *(short4*)&s_dh[0][off] = z; *(short4*)&s_dl[0][off] = z;
        *(short4*)&s_dh[1][off] = z; *(short4*)&s_dl[1][off] = z;
    }

    // stage: mask+split+store one chunk, accumulate & publish ssq partials
    auto stage = [&](short* dh, short* dl, float* ssqw,
                     float4 a0, float4 a1, float4 a2) {
        float4 ps = make_float4(0.f, 0.f, 0.f, 0.f);
        {
            float4 v = a0;
            v.x *= mk0; v.y *= mk0; v.z *= mk0; v.w *= mk0;
            ps.x += v.x*v.x; ps.y += v.y*v.y; ps.z += v.z*v.z; ps.w += v.w*v.w;
            short4 h, lo;
            split2(v.x, h.x, lo.x); split2(v.y, h.y, lo.y);
            split2(v.z, h.z, lo.z); split2(v.w, h.w, lo.w);
            *(short4*)&dh[rb * PB + 4 * d4] = h;
            *(short4*)&dl[rb * PB + 4 * d4] = lo;
        }
        {
            float4 v = a1;
            v.x *= mk1; v.y *= mk1; v.z *= mk1; v.w *= mk1;
            ps.x += v.x*v.x; ps.y += v.y*v.y; ps.z += v.z*v.z; ps.w += v.w*v.w;
            short4 h, lo;
            split2(v.x, h.x, lo.x); split2(v.y, h.y, lo.y);
            split2(v.z, h.z, lo.z); split2(v.w, h.w, lo.w);
            *(short4*)&dh[(rb + 64) * PB + 4 * d4] = h;
            *(short4*)&dl[(rb + 64) * PB + 4 * d4] = lo;
        }
        if (has2) {
            float4 v = a2;
            v.x *= mk2; v.y *= mk2; v.z *= mk2; v.w *= mk2;
            ps.x += v.x*v.x; ps.y += v.y*v.y; ps.z += v.z*v.z; ps.w += v.w*v.w;
            short4 h, lo;
            split2(v.x, h.x, lo.x); split2(v.y, h.y, lo.y);
            split2(v.z, h.z, lo.z); split2(v.w, h.w, lo.w);
            *(short4*)&dh[(rb + 128) * PB + 4 * d4] = h;
            *(short4*)&dl[(rb + 128) * PB + 4 * d4] = lo;
        }
        #pragma unroll
        for (int off = 8; off <= 32; off <<= 1) {
            ps.x += __shfl_xor(ps.x, off);
            ps.y += __shfl_xor(ps.y, off);
            ps.z += __shfl_xor(ps.z, off);
            ps.w += __shfl_xor(ps.w, off);
        }
        if (lane < 8) *(float4*)&ssqw[wave * 32 + 4 * lane] = ps;
    };

    // ---- prologue: chunk 0 staged + normalized (serial, once) ----
    stage(s_dh[0], s_dl[0], &s_ssq[0][0][0], dv0, dv1, dv2);
    dv0 = doc4[rb * 32 + 8 + d4];              // chunk-1 prefetch
    dv1 = doc4[(rb + 64) * 32 + 8 + d4];
    if (has2) dv2 = doc4[(rb + 128) * 32 + 8 + d4];
    bar();
    if (t < 32) {
        float tot = 0.f;
        #pragma unroll
        for (int w = 0; w < 8; ++w) tot += s_ssq[0][w][t];
        s_dinv[0][0][t] = 1.0f / fmaxf(sqrtf(tot), 1e-12f);
    }
    bar();
    if (t < 256) {
        float qi = s_qinv[rb];
        float4 dvec = *(const float4*)&s_dinv[0][0][4 * d4];
        float4 v = qv0;
        v.x *= qi * dvec.x; v.y *= qi * dvec.y;
        v.z *= qi * dvec.z; v.w *= qi * dvec.w;
        short4 h, lo;
        split2(v.x, h.x, lo.x); split2(v.y, h.y, lo.y);
        split2(v.z, h.z, lo.z); split2(v.w, h.w, lo.w);
        *(short4*)&s_qh[0][rb * PB + 4 * d4] = h;
        *(short4*)&s_ql[0][rb * PB + 4 * d4] = lo;
    }
    bar();

    // ---- main loop ----
    f32x16 acc = {};
    #pragma unroll
    for (int cc = 0; cc < 4; ++cc) {
        const int Bc = cc & 1, Bn = Bc ^ 1;
        if (cc < 3) {
            if (wave >= 6) {                   // issue q loads for fold(cc+1)
                int f = (wave - 6) * 64 + lane;
                qf0 = q4g[(f >> 3) * 32 + (cc + 1) * 8 + (f & 7)];
                qf1 = q4g[((f >> 3) + 16) * 32 + (cc + 1) * 8 + (f & 7)];
            }
            stage(s_dh[Bn], s_dl[Bn], &s_ssq[Bn][0][0], dv0, dv1, dv2);
            if (cc < 2) {                      // prefetch chunk cc+2
                dv0 = doc4[rb * 32 + (cc + 2) * 8 + d4];
                dv1 = doc4[(rb + 64) * 32 + (cc + 2) * 8 + d4];
                if (has2) dv2 = doc4[(rb + 128) * 32 + (cc + 2) * 8 + d4];
            }
        }
        bar();                                 // staging cc+1 visible; bufA free-to-read
        if (wave < 6) {
            // MFMA chunk cc (buf Bc)
            #pragma unroll
            for (int kk = 0; kk < 2; ++kk) {
                int ao = l31 * PB + 16 * kk + 8 * lh;
                short8v ah = *(const short8v*)&s_qh[Bc][ao];
                short8v al = *(const short8v*)&s_ql[Bc][ao];
                int bo = (32 * wave + l31) * PB + 16 * kk + 8 * lh;
                short8v bh = *(const short8v*)&s_dh[Bc][bo];
                short8v bl = *(const short8v*)&s_dl[Bc][bo];
                acc = __builtin_amdgcn_mfma_f32_32x32x16_bf16(ah, bh, acc, 0, 0, 0);
                acc = __builtin_amdgcn_mfma_f32_32x32x16_bf16(ah, bl, acc, 0, 0, 0);
                acc = __builtin_amdgcn_mfma_f32_32x32x16_bf16(al, bh, acc, 0, 0, 0);
            }
        } else if (cc < 3) {
            // dinv(cc+1): private per-wave copy (no cross-wave dep)
            const int w6 = wave - 6;
            float tot = 0.f;
            #pragma unroll
            for (int w = 0; w < 8; ++w) tot += s_ssq[Bn][w][l31];
            float di = 1.0f / fmaxf(sqrtf(tot), 1e-12f);
            if (lane < 32) s_dinv[Bn][w6][l31] = di;
            asm volatile("s_waitcnt lgkmcnt(0)" ::: "memory");
            // fold q'(cc+1): 128 threads x 2 float4
            int f = w6 * 64 + lane;
            int r0 = f >> 3, d4p = f & 7;
            float4 dvec = *(const float4*)&s_dinv[Bn][w6][4 * d4p];
            float qi0 = s_qinv[r0], qi1 = s_qinv[r0 + 16];
            {
                float4 v = qf0;
                v.x *= qi0 * dvec.x; v.y *= qi0 * dvec.y;
                v.z *= qi0 * dvec.z; v.w *= qi0 * dvec.w;
                short4 h, lo;
                split2(v.x, h.x, lo.x); split2(v.y, h.y, lo.y);
                split2(v.z, h.z, lo.z); split2(v.w, h.w, lo.w);
                *(short4*)&s_qh[Bn][r0 * PB + 4 * d4p] = h;
                *(short4*)&s_ql[Bn][r0 * PB + 4 * d4p] = lo;
            }
            {
                float4 v = qf1;
                v.x *= qi1 * dvec.x; v.y *= qi1 * dvec.y;
                v.z *= qi1 * dvec.z; v.w *= qi1 * dvec.w;
                short4 h, lo;
                split2(v.x, h.x, lo.x); split2(v.y, h.y, lo.y);
                split2(v.z, h.z, lo.z); split2(v.w, h.w, lo.w);
                *(short4*)&s_qh[Bn][(r0 + 16) * PB + 4 * d4p] = h;
                *(short4*)&s_ql[Bn][(r0 + 16) * PB + 4 * d4p] = lo;
            }
        }
        if (cc < 3) bar();                     // bufA free-to-write; fold visible
    }

    // ---- epilogue: per-q-row max over doc tokens, sum over q rows ----
    if (wave < 6) {
        float pm[16];
        #pragma unroll
        for (int r = 0; r < 16; ++r) pm[r] = acc[r];
        #pragma unroll
        for (int off = 1; off <= 16; off <<= 1)
            #pragma unroll
            for (int r = 0; r < 16; ++r)
                pm[r] = fmaxf(pm[r], __shfl_xor(pm[r], off));
        if (l31 == 0) {
            #pragma unroll
            for (int r = 0; r < 16; ++r)
                s_pm[wave][(r & 3) + 8 * (r >> 2) + 4 * lh] = pm[r];
        }
    }
    bar();
    if (t < 32) {
        float v = s_pm[0][t];
        #pragma unroll
        for (int w = 1; w < 6; ++w) v = fmaxf(v, s_pm[w][t]);
        #pragma unroll
        for (int off = 16; off >= 1; off >>= 1) v += __shfl_xor(v, off);
        if (t == 0) scores[bw] = v;
    }
}

// ---------- finisher: log-softmax over W + KLDiv(log_target, batchmean) ----------
__global__ __launch_bounds__(NB) void finish_kernel(
    const float* __restrict__ scores, const float* __restrict__ labels,
    float* __restrict__ out)
{
    __shared__ float s_part[2];
    const int t = threadIdx.x;
    const float* sr = scores + t * NW;
    const float* lr = labels + t * NW;

    float s[NW];
    float m = -INFINITY;
    #pragma unroll
    for (int w = 0; w < NW; ++w) { s[w] = sr[w]; m = fmaxf(m, s[w]); }
    float se = 0.f;
    #pragma unroll
    for (int w = 0; w < NW; ++w) se += expf(s[w] - m);
    float lse = logf(se) + m;

    float term = 0.f;
    #pragma unroll
    for (int w = 0; w < NW; ++w) {
        float lw = lr[w];
        term += expf(lw) * (lw - (s[w] - lse));
    }
    #pragma unroll
    for (int off = 32; off > 0; off >>= 1) term += __shfl_xor(term, off);
    if ((t & 63) == 0) s_part[t >> 6] = term;
    __syncthreads();
    if (t == 0) out[0] = (s_part[0] + s_part[1]) / (float)NB;
}

extern "C" void kernel_launch(void* const* d_in, const int* in_sizes, int n_in,
                              void* d_out, int out_size, void* d_ws, size_t ws_size,
                              hipStream_t stream) {
    const float* qreps  = (const float*)d_in[0];
    const float* dreps  = (const float*)d_in[1];
    const int*   dmask  = (const int*)d_in[2];
    const float* labels = (const float*)d_in[3];
    float* out = (float*)d_out;
    float* scores = (float*)d_ws;   // NBW floats

    maxsim_kernel<<<NBW, 512, 0, stream>>>(qreps, dreps, dmask, scores);
    finish_kernel<<<1, NB, 0, stream>>>(scores, labels, out);
}